// Round 1
// baseline (1648.180 us; speedup 1.0000x reference)
//
#include <hip/hip_runtime.h>

// ComplexFaberConv: degree-normalized directed SpMM + collapsed complex linear.
//
// Math (derived from reference, all linear in k so W-stacks collapse):
//   WrE = sum_k 0.5^k W_real[k], WiE likewise; brE, biE likewise.
//   S_i = y_imag + y_imag_t  (only the sum is ever used)
//   total_real = 0.5*(y_real+y_real_t)@WrE^T - 0.5*S_i@WiE^T + (brE-biE)
//   total_imag = y_real@WiE^T + 0.5*S_i@WrE^T + (brE+biE)
// (reference faithfully uses y_real, not y_real_t, in sum_imag_d2s)

constexpr int D = 64;

__global__ void degree_kernel(const int* __restrict__ row, const int* __restrict__ col,
                              float* __restrict__ deg_out, float* __restrict__ deg_in, int E) {
  int e = blockIdx.x * blockDim.x + threadIdx.x;
  if (e < E) {
    atomicAdd(&deg_out[row[e]], 1.0f);
    atomicAdd(&deg_in[col[e]], 1.0f);
  }
}

// deg -> deg^-0.25 (0 if deg==0), in place, over 2N contiguous floats
__global__ void inv_kernel(float* __restrict__ deg, int count) {
  int i = blockIdx.x * blockDim.x + threadIdx.x;
  if (i < count) {
    float d = deg[i];
    deg[i] = (d > 0.0f) ? rsqrtf(sqrtf(d)) : 0.0f;
  }
}

// Collapse K=3 weight stacks; store transposed WT[d*64+o] = WE[o][d].
__global__ void weights_kernel(const float* __restrict__ Wr, const float* __restrict__ br,
                               const float* __restrict__ Wi, const float* __restrict__ bi,
                               float* __restrict__ WrT, float* __restrict__ WiT,
                               float* __restrict__ cR, float* __restrict__ cI) {
  int i = blockIdx.x * blockDim.x + threadIdx.x;  // 0..4095 -> (o,d)
  if (i < 4096) {
    int o = i >> 6, d = i & 63;
    float wr = Wr[i] + 0.5f * Wr[4096 + i] + 0.25f * Wr[8192 + i];
    float wi = Wi[i] + 0.5f * Wi[4096 + i] + 0.25f * Wi[8192 + i];
    WrT[d * 64 + o] = wr;
    WiT[d * 64 + o] = wi;
    if (i < 64) {
      float brv = br[i] + 0.5f * br[64 + i] + 0.25f * br[128 + i];
      float biv = bi[i] + 0.5f * bi[64 + i] + 0.25f * bi[128 + i];
      cR[i] = brv - biv;
      cI[i] = brv + biv;
    }
  }
}

// One wave per edge (lane = feature). Both scatter directions fused:
//   y_real[r]   += w*x_real[c];  S_i[r] += w*x_imag[c];
//   y_real_t[c] += w*x_real[r];  S_i[c] += w*x_imag[r];
__global__ __launch_bounds__(256) void scatter_kernel(
    const float* __restrict__ x_real, const float* __restrict__ x_imag,
    const int* __restrict__ row, const int* __restrict__ col,
    const float* __restrict__ inv_out, const float* __restrict__ inv_in,
    float* __restrict__ y_real, float* __restrict__ y_real_t, float* __restrict__ s_imag,
    int E) {
  int lane = threadIdx.x & 63;
  int wave = (blockIdx.x * blockDim.x + threadIdx.x) >> 6;
  int nwaves = (gridDim.x * blockDim.x) >> 6;
  for (int e = wave; e < E; e += nwaves) {
    int r = row[e];
    int c = col[e];
    float w = inv_out[r] * inv_in[c];
    size_t rb = (size_t)r * D + lane;
    size_t cb = (size_t)c * D + lane;
    float xr_c = x_real[cb], xi_c = x_imag[cb];
    float xr_r = x_real[rb], xi_r = x_imag[rb];
    atomicAdd(&y_real[rb],   w * xr_c);
    atomicAdd(&s_imag[rb],   w * xi_c);
    atomicAdd(&y_real_t[cb], w * xr_r);
    atomicAdd(&s_imag[cb],   w * xi_r);
  }
}

// Fused epilogue GEMM: lane = output feature o, 4 nodes per wave-iteration.
// Weights transposed in LDS (conflict-free b32 across lanes); per-node input
// vectors interleaved [d][slot] so one b128 broadcast feeds all 4 nodes.
#define NB 4
__global__ __launch_bounds__(256) void output_kernel(
    const float* __restrict__ y_real, const float* __restrict__ y_real_t,
    const float* __restrict__ s_imag,
    const float* __restrict__ WrT, const float* __restrict__ WiT,
    const float* __restrict__ cR, const float* __restrict__ cI,
    float* __restrict__ out_real, float* __restrict__ out_imag, int n_nodes) {
  __shared__ float sWr[4096];
  __shared__ float sWi[4096];
  __shared__ float sP[4][64 * NB];
  __shared__ float sQ[4][64 * NB];
  __shared__ float sR[4][64 * NB];
  __shared__ float sT[4][64 * NB];
  for (int i = threadIdx.x; i < 4096; i += 256) {
    sWr[i] = WrT[i];
    sWi[i] = WiT[i];
  }
  __syncthreads();
  int wave = threadIdx.x >> 6;
  int lane = threadIdx.x & 63;
  float creal = cR[lane];
  float cimag = cI[lane];
  int stride = gridDim.x * 4 * NB;
  for (int n0 = (blockIdx.x * 4 + wave) * NB; n0 < n_nodes; n0 += stride) {
    int nb = min(NB, n_nodes - n0);
    float accR[NB], accI[NB];
#pragma unroll
    for (int j = 0; j < NB; ++j) {
      int n = n0 + (j < nb ? j : 0);  // clamp; extras not stored
      float u = y_real[(size_t)n * D + lane];
      float v = y_real_t[(size_t)n * D + lane];
      float s = s_imag[(size_t)n * D + lane];
      sP[wave][lane * NB + j] = 0.5f * (u + v);
      sQ[wave][lane * NB + j] = -0.5f * s;
      sR[wave][lane * NB + j] = 0.5f * s;
      sT[wave][lane * NB + j] = u;
      accR[j] = creal;
      accI[j] = cimag;
    }
    // wave-synchronous LDS RAW: compiler inserts lgkmcnt waits (same-wave DS in order)
#pragma unroll 4
    for (int d = 0; d < 64; ++d) {
      float wr = sWr[d * 64 + lane];
      float wi = sWi[d * 64 + lane];
      const float4 p = *(const float4*)&sP[wave][d * NB];
      const float4 q = *(const float4*)&sQ[wave][d * NB];
      const float4 r = *(const float4*)&sR[wave][d * NB];
      const float4 t = *(const float4*)&sT[wave][d * NB];
      accR[0] += p.x * wr + q.x * wi;  accI[0] += r.x * wr + t.x * wi;
      accR[1] += p.y * wr + q.y * wi;  accI[1] += r.y * wr + t.y * wi;
      accR[2] += p.z * wr + q.z * wi;  accI[2] += r.z * wr + t.z * wi;
      accR[3] += p.w * wr + q.w * wi;  accI[3] += r.w * wr + t.w * wi;
    }
#pragma unroll
    for (int j = 0; j < NB; ++j) {
      if (j < nb) {
        out_real[(size_t)(n0 + j) * D + lane] = accR[j];
        out_imag[(size_t)(n0 + j) * D + lane] = accI[j];
      }
    }
  }
}

extern "C" void kernel_launch(void* const* d_in, const int* in_sizes, int n_in,
                              void* d_out, int out_size, void* d_ws, size_t ws_size,
                              hipStream_t stream) {
  const float* x_real = (const float*)d_in[0];
  const float* x_imag = (const float*)d_in[1];
  const int* edge = (const int*)d_in[2];
  const float* W_real = (const float*)d_in[3];
  const float* b_real = (const float*)d_in[4];
  const float* W_imag = (const float*)d_in[5];
  const float* b_imag = (const float*)d_in[6];

  const int N = in_sizes[0] / D;      // 100000
  const int E = in_sizes[2] / 2;      // 1600000
  const int* row = edge;
  const int* col = edge + E;

  float* ws = (float*)d_ws;
  float* y_real   = ws;                          // N*64
  float* y_real_t = ws + (size_t)N * D;          // N*64
  float* s_imag   = ws + (size_t)2 * N * D;      // N*64
  float* deg_out  = ws + (size_t)3 * N * D;      // N (becomes inv_out)
  float* deg_in   = deg_out + N;                 // N (becomes inv_in)
  float* WrT      = deg_in + N;                  // 4096
  float* WiT      = WrT + 4096;                  // 4096
  float* cR       = WiT + 4096;                  // 64
  float* cI       = cR + 64;                     // 64

  float* out_real = (float*)d_out;
  float* out_imag = out_real + (size_t)N * D;

  // zero accumulators + degree counters (ws is poisoned before every launch)
  size_t zero_bytes = ((size_t)3 * N * D + 2 * (size_t)N) * sizeof(float);
  hipMemsetAsync(d_ws, 0, zero_bytes, stream);

  degree_kernel<<<(E + 255) / 256, 256, 0, stream>>>(row, col, deg_out, deg_in, E);
  inv_kernel<<<(2 * N + 255) / 256, 256, 0, stream>>>(deg_out, 2 * N);
  weights_kernel<<<16, 256, 0, stream>>>(W_real, b_real, W_imag, b_imag, WrT, WiT, cR, cI);
  scatter_kernel<<<4096, 256, 0, stream>>>(x_real, x_imag, row, col, deg_out, deg_in,
                                           y_real, y_real_t, s_imag, E);
  output_kernel<<<2048, 256, 0, stream>>>(y_real, y_real_t, s_imag, WrT, WiT, cR, cI,
                                          out_real, out_imag, N);
}

// Round 2
// 1004.857 us; speedup vs baseline: 1.6402x; 1.6402x over previous
//
#include <hip/hip_runtime.h>

// ComplexFaberConv: degree-normalized directed SpMM + collapsed complex linear.
//
// Math (linear in k, so W-stacks collapse):
//   WrE = sum_k 0.5^k W_real[k], WiE likewise; brE, biE likewise.
//   u = y_real, v = y_real_t, S = y_imag + y_imag_t
//   total_real = 0.5*(u+v)@WrE^T - 0.5*S@WiE^T + (brE-biE)
//   total_imag = u@WiE^T + 0.5*S@WrE^T + (brE+biE)
// (reference faithfully uses y_real, not y_real_t, in sum_imag_d2s)
//
// R2: atomic-free SpMM. R1 scatter was atomic-RMW bound (WRITE_SIZE == 4B x
// every lane-atomic). Build dual CSR on device, then gather per node in
// registers; fuse the 64x128 linear epilogue (weights in LDS).

constexpr int D = 64;

__global__ void degree_kernel(const int* __restrict__ row, const int* __restrict__ col,
                              int* __restrict__ deg_out, int* __restrict__ deg_in, int E) {
  int e = blockIdx.x * blockDim.x + threadIdx.x;
  if (e < E) {
    atomicAdd(&deg_out[row[e]], 1);
    atomicAdd(&deg_in[col[e]], 1);
  }
}

// One block per array (grid.x = 2): exclusive scan of degrees -> ofs[N+1],
// plus inv[i] = deg^-0.25 (0 if deg==0).
__global__ __launch_bounds__(1024) void scan_kernel(
    const int* __restrict__ deg_out, const int* __restrict__ deg_in,
    int* __restrict__ ofs_out, int* __restrict__ ofs_in,
    float* __restrict__ inv_out, float* __restrict__ inv_in, int N) {
  const int* deg = blockIdx.x ? deg_in : deg_out;
  int* ofs = blockIdx.x ? ofs_in : ofs_out;
  float* inv = blockIdx.x ? inv_in : inv_out;
  __shared__ int ps[1024];
  int t = threadIdx.x;
  int chunk = (N + 1023) >> 10;
  int b = t * chunk, e = min(N, b + chunk);
  int s = 0;
  for (int i = b; i < e; ++i) {
    int d = deg[i];
    s += d;
    inv[i] = d > 0 ? rsqrtf(sqrtf((float)d)) : 0.0f;
  }
  ps[t] = s;
  __syncthreads();
  for (int off = 1; off < 1024; off <<= 1) {  // inclusive Hillis-Steele
    int v = (t >= off) ? ps[t - off] : 0;
    __syncthreads();
    ps[t] += v;
    __syncthreads();
  }
  int run = ps[t] - s;  // exclusive prefix
  for (int i = b; i < e; ++i) {
    ofs[i] = run;
    run += deg[i];
  }
  if (b < N && e == N) ofs[N] = run;
}

// Place (neighbor, weight) into both CSRs. Order within a bucket is arbitrary.
__global__ void fill_kernel(const int* __restrict__ row, const int* __restrict__ col,
                            const float* __restrict__ inv_out, const float* __restrict__ inv_in,
                            const int* __restrict__ ofs_out, const int* __restrict__ ofs_in,
                            int* __restrict__ cur_out, int* __restrict__ cur_in,
                            uint2* __restrict__ csr_out, uint2* __restrict__ csr_in, int E) {
  int e = blockIdx.x * blockDim.x + threadIdx.x;
  if (e < E) {
    int r = row[e], c = col[e];
    float w = inv_out[r] * inv_in[c];
    int po = ofs_out[r] + atomicAdd(&cur_out[r], 1);
    csr_out[po] = make_uint2((unsigned)c, __float_as_uint(w));
    int pi = ofs_in[c] + atomicAdd(&cur_in[c], 1);
    csr_in[pi] = make_uint2((unsigned)r, __float_as_uint(w));
  }
}

// Collapse K=3 weight stacks; store interleaved-transposed:
//   WT2[d*128 + 2*o] = WrE[o][d], WT2[d*128 + 2*o + 1] = WiE[o][d]
__global__ void weights_kernel(const float* __restrict__ Wr, const float* __restrict__ br,
                               const float* __restrict__ Wi, const float* __restrict__ bi,
                               float* __restrict__ WT2, float* __restrict__ cR,
                               float* __restrict__ cI) {
  int i = blockIdx.x * blockDim.x + threadIdx.x;  // 0..4095 -> (o,d)
  if (i < 4096) {
    int o = i >> 6, d = i & 63;
    float wr = Wr[i] + 0.5f * Wr[4096 + i] + 0.25f * Wr[8192 + i];
    float wi = Wi[i] + 0.5f * Wi[4096 + i] + 0.25f * Wi[8192 + i];
    WT2[d * 128 + 2 * o] = wr;
    WT2[d * 128 + 2 * o + 1] = wi;
    if (i < 64) {
      float brv = br[i] + 0.5f * br[64 + i] + 0.25f * br[128 + i];
      float biv = bi[i] + 0.5f * bi[64 + i] + 0.25f * bi[128 + i];
      cR[i] = brv - biv;
      cI[i] = brv + biv;
    }
  }
}

// One wave per node (lane = feature). Register-accumulated gather over both
// CSR directions, then fused complex linear via LDS-resident weights.
__global__ __launch_bounds__(256) void gather_kernel(
    const float* __restrict__ x_real, const float* __restrict__ x_imag,
    const uint2* __restrict__ csr_out, const uint2* __restrict__ csr_in,
    const int* __restrict__ ofs_out, const int* __restrict__ ofs_in,
    const float* __restrict__ WT2, const float* __restrict__ cR, const float* __restrict__ cI,
    float* __restrict__ out_real, float* __restrict__ out_imag, int N) {
  __shared__ float sW[8192];        // 32 KB interleaved (wr,wi) weights
  __shared__ float sV[4][64 * 4];   // per-wave staging: {p, sh, u, pad} per d
  for (int i = threadIdx.x; i < 8192; i += 256) sW[i] = WT2[i];
  __syncthreads();
  int wv = threadIdx.x >> 6, lane = threadIdx.x & 63;
  float cRv = cR[lane], cIv = cI[lane];
  float* mv = &sV[wv][0];
  int wid = blockIdx.x * 4 + wv;
  int nw = gridDim.x * 4;
  for (int n = wid; n < N; n += nw) {
    float u = 0.0f, v = 0.0f, s = 0.0f;
    {  // out-direction: u += w*x_real[c], s += w*x_imag[c]
      int b1 = ofs_out[n + 1];
      int j = ofs_out[n];
      for (; j + 2 <= b1; j += 2) {
        uint2 e0 = csr_out[j], e1 = csr_out[j + 1];
        size_t a0 = (size_t)e0.x * D + lane, a1 = (size_t)e1.x * D + lane;
        float w0 = __uint_as_float(e0.y), w1 = __uint_as_float(e1.y);
        float xr0 = x_real[a0], xi0 = x_imag[a0];
        float xr1 = x_real[a1], xi1 = x_imag[a1];
        u += w0 * xr0 + w1 * xr1;
        s += w0 * xi0 + w1 * xi1;
      }
      if (j < b1) {
        uint2 e0 = csr_out[j];
        size_t a0 = (size_t)e0.x * D + lane;
        float w0 = __uint_as_float(e0.y);
        u += w0 * x_real[a0];
        s += w0 * x_imag[a0];
      }
    }
    {  // in-direction: v += w*x_real[r], s += w*x_imag[r]
      int b1 = ofs_in[n + 1];
      int j = ofs_in[n];
      for (; j + 2 <= b1; j += 2) {
        uint2 e0 = csr_in[j], e1 = csr_in[j + 1];
        size_t a0 = (size_t)e0.x * D + lane, a1 = (size_t)e1.x * D + lane;
        float w0 = __uint_as_float(e0.y), w1 = __uint_as_float(e1.y);
        float xr0 = x_real[a0], xi0 = x_imag[a0];
        float xr1 = x_real[a1], xi1 = x_imag[a1];
        v += w0 * xr0 + w1 * xr1;
        s += w0 * xi0 + w1 * xi1;
      }
      if (j < b1) {
        uint2 e0 = csr_in[j];
        size_t a0 = (size_t)e0.x * D + lane;
        float w0 = __uint_as_float(e0.y);
        v += w0 * x_real[a0];
        s += w0 * x_imag[a0];
      }
    }
    // epilogue: accR = cR + sum_d p*wr - sh*wi ; accI = cI + sum_d sh*wr + u*wi
    ((float4*)mv)[lane] = make_float4(0.5f * (u + v), 0.5f * s, u, 0.0f);
    // wave-synchronous LDS RAW: same-wave DS ops are ordered via lgkmcnt
    float accR = cRv, accI = cIv;
#pragma unroll 4
    for (int d = 0; d < 64; ++d) {
      float4 pv = ((const float4*)mv)[d];                   // broadcast b128
      float2 w2 = *(const float2*)&sW[d * 128 + 2 * lane];  // b64, 2-way (free)
      accR += pv.x * w2.x - pv.y * w2.y;
      accI += pv.y * w2.x + pv.z * w2.y;
    }
    out_real[(size_t)n * D + lane] = accR;
    out_imag[(size_t)n * D + lane] = accI;
  }
}

extern "C" void kernel_launch(void* const* d_in, const int* in_sizes, int n_in,
                              void* d_out, int out_size, void* d_ws, size_t ws_size,
                              hipStream_t stream) {
  const float* x_real = (const float*)d_in[0];
  const float* x_imag = (const float*)d_in[1];
  const int* edge = (const int*)d_in[2];
  const float* W_real = (const float*)d_in[3];
  const float* b_real = (const float*)d_in[4];
  const float* W_imag = (const float*)d_in[5];
  const float* b_imag = (const float*)d_in[6];

  const int N = in_sizes[0] / D;  // 100000
  const int E = in_sizes[2] / 2;  // 1600000
  const int* row = edge;
  const int* col = edge + E;

  // workspace layout (csr first for 8B alignment)
  uint2* csr_out = (uint2*)d_ws;              // E
  uint2* csr_in  = csr_out + E;               // E
  int* deg_out   = (int*)(csr_in + E);        // N  -- zeroed
  int* deg_in    = deg_out + N;               // N  -- zeroed
  int* cur_out   = deg_in + N;                // N  -- zeroed
  int* cur_in    = cur_out + N;               // N  -- zeroed
  int* ofs_out   = cur_in + N;                // N+1
  int* ofs_in    = ofs_out + N + 1;           // N+1
  float* inv_out = (float*)(ofs_in + N + 1);  // N
  float* inv_in  = inv_out + N;               // N
  float* WT2     = inv_in + N;                // 8192
  float* cR      = WT2 + 8192;                // 64
  float* cI      = cR + 64;                   // 64

  float* out_real = (float*)d_out;
  float* out_imag = out_real + (size_t)N * D;

  hipMemsetAsync(deg_out, 0, (size_t)4 * N * sizeof(int), stream);

  degree_kernel<<<(E + 255) / 256, 256, 0, stream>>>(row, col, deg_out, deg_in, E);
  scan_kernel<<<2, 1024, 0, stream>>>(deg_out, deg_in, ofs_out, ofs_in, inv_out, inv_in, N);
  weights_kernel<<<16, 256, 0, stream>>>(W_real, b_real, W_imag, b_imag, WT2, cR, cI);
  fill_kernel<<<(E + 255) / 256, 256, 0, stream>>>(row, col, inv_out, inv_in, ofs_out, ofs_in,
                                                   cur_out, cur_in, csr_out, csr_in, E);
  gather_kernel<<<2048, 256, 0, stream>>>(x_real, x_imag, csr_out, csr_in, ofs_out, ofs_in,
                                          WT2, cR, cI, out_real, out_imag, N);
}

// Round 3
// 956.437 us; speedup vs baseline: 1.7233x; 1.0506x over previous
//
#include <hip/hip_runtime.h>
#include <hip/hip_fp16.h>

// ComplexFaberConv: degree-normalized directed SpMM + collapsed complex linear.
//
// Math (linear in k, so W-stacks collapse):
//   WrE = sum_k 0.5^k W_real[k], WiE likewise; brE, biE likewise.
//   u = y_real, v = y_real_t, S = y_imag + y_imag_t
//   total_real = 0.5*(u+v)@WrE^T - 0.5*S@WiE^T + (brE-biE)
//   total_imag = u@WiE^T + 0.5*S@WrE^T + (brE+biE)
// (reference faithfully uses y_real, not y_real_t, in sum_imag_d2s)
//
// R3: gather was latency-bound (occ 42%, VALU 31%, hbm 26%). Pack x as
// pre-scaled half2 (one dword gather per edge-direction, half the bytes),
// index-only CSR (4B), half2 weights in LDS (20KB -> 8 blocks/CU).

constexpr int D = 64;

__device__ __forceinline__ float2 h2_to_f2(uint p) {
  __half2 h = *(__half2*)&p;
  return __half22float2(h);
}

__global__ void degree_kernel(const int* __restrict__ row, const int* __restrict__ col,
                              int* __restrict__ deg_out, int* __restrict__ deg_in, int E) {
  int e = blockIdx.x * blockDim.x + threadIdx.x;
  if (e < E) {
    atomicAdd(&deg_out[row[e]], 1);
    atomicAdd(&deg_in[col[e]], 1);
  }
}

// One block per array (grid.x = 2): exclusive scan of degrees -> ofs,
// plus inv[i] = deg^-0.25 (0 if deg==0).
__global__ __launch_bounds__(1024) void scan_kernel(
    const int* __restrict__ deg_out, const int* __restrict__ deg_in,
    int* __restrict__ ofs_out, int* __restrict__ ofs_in,
    float* __restrict__ inv_out, float* __restrict__ inv_in, int N) {
  const int* deg = blockIdx.x ? deg_in : deg_out;
  int* ofs = blockIdx.x ? ofs_in : ofs_out;
  float* inv = blockIdx.x ? inv_in : inv_out;
  __shared__ int ps[1024];
  int t = threadIdx.x;
  int chunk = (N + 1023) >> 10;
  int b = t * chunk, e = min(N, b + chunk);
  int s = 0;
  for (int i = b; i < e; ++i) {
    int d = deg[i];
    s += d;
    inv[i] = d > 0 ? rsqrtf(sqrtf((float)d)) : 0.0f;
  }
  ps[t] = s;
  __syncthreads();
  for (int off = 1; off < 1024; off <<= 1) {  // inclusive Hillis-Steele
    int v = (t >= off) ? ps[t - off] : 0;
    __syncthreads();
    ps[t] += v;
    __syncthreads();
  }
  int run = ps[t] - s;  // exclusive prefix
  for (int i = b; i < e; ++i) {
    ofs[i] = run;
    run += deg[i];
  }
}

// Pre-scaled packed features:
//   xin_p[n*64+d]  = half2(inv_in[n]*xr,  inv_in[n]*xi)   (gathered by out-dir)
//   xout_p[n*64+d] = half2(inv_out[n]*xr, inv_out[n]*xi)  (gathered by in-dir)
__global__ void pack_kernel(const float* __restrict__ xr, const float* __restrict__ xi,
                            const float* __restrict__ inv_out, const float* __restrict__ inv_in,
                            uint* __restrict__ xout_p, uint* __restrict__ xin_p, int total) {
  int i = blockIdx.x * blockDim.x + threadIdx.x;
  if (i < total) {
    int n = i >> 6;
    float a = xr[i], b = xi[i];
    float io = inv_out[n], ii = inv_in[n];
    __half2 ho = __floats2half2_rn(io * a, io * b);
    __half2 hi = __floats2half2_rn(ii * a, ii * b);
    xout_p[i] = *(uint*)&ho;
    xin_p[i] = *(uint*)&hi;
  }
}

// Index-only CSR fill; ofs arrays double as cursors (after fill,
// ofs[n] = end of bucket n; bucket n = [n ? ofs[n-1] : 0, ofs[n]) ).
__global__ void fill_kernel(const int* __restrict__ row, const int* __restrict__ col,
                            int* __restrict__ ofs_out, int* __restrict__ ofs_in,
                            uint* __restrict__ idx_out, uint* __restrict__ idx_in, int E) {
  int e = blockIdx.x * blockDim.x + threadIdx.x;
  if (e < E) {
    int r = row[e], c = col[e];
    idx_out[atomicAdd(&ofs_out[r], 1)] = (uint)c;
    idx_in[atomicAdd(&ofs_in[c], 1)] = (uint)r;
  }
}

// Collapse K=3 weight stacks; pack (wr,wi) as half2: Wh[d*64+o].
__global__ void weights_kernel(const float* __restrict__ Wr, const float* __restrict__ br,
                               const float* __restrict__ Wi, const float* __restrict__ bi,
                               uint* __restrict__ Wh, float* __restrict__ cR,
                               float* __restrict__ cI) {
  int i = blockIdx.x * blockDim.x + threadIdx.x;  // 0..4095 -> (o,d)
  if (i < 4096) {
    int o = i >> 6, d = i & 63;
    float wr = Wr[i] + 0.5f * Wr[4096 + i] + 0.25f * Wr[8192 + i];
    float wi = Wi[i] + 0.5f * Wi[4096 + i] + 0.25f * Wi[8192 + i];
    __half2 h = __floats2half2_rn(wr, wi);
    Wh[d * 64 + o] = *(uint*)&h;
    if (i < 64) {
      float brv = br[i] + 0.5f * br[64 + i] + 0.25f * br[128 + i];
      float biv = bi[i] + 0.5f * bi[64 + i] + 0.25f * bi[128 + i];
      cR[i] = brv - biv;
      cI[i] = brv + biv;
    }
  }
}

// One wave per node (lane = feature). One dword gather per edge-direction,
// register accumulation, fused complex linear epilogue (half2 weights in LDS).
__global__ __launch_bounds__(256) void gather_kernel(
    const uint* __restrict__ xout_p, const uint* __restrict__ xin_p,
    const uint* __restrict__ idx_out, const uint* __restrict__ idx_in,
    const int* __restrict__ ofs_out, const int* __restrict__ ofs_in,
    const float* __restrict__ inv_out, const float* __restrict__ inv_in,
    const uint* __restrict__ Wh, const float* __restrict__ cR, const float* __restrict__ cI,
    float* __restrict__ out_real, float* __restrict__ out_imag, int N) {
  __shared__ uint sW[4096];        // 16 KB half2 weights
  __shared__ float4 sV[4][64];     // 4 KB per-wave staging
  for (int i = threadIdx.x; i < 4096; i += 256) sW[i] = Wh[i];
  __syncthreads();
  int wv = __builtin_amdgcn_readfirstlane(threadIdx.x >> 6);
  int lane = threadIdx.x & 63;
  float cRv = cR[lane], cIv = cI[lane];
  float4* mv = &sV[wv][0];
  int wid = blockIdx.x * 4 + wv;
  int nw = gridDim.x * 4;
  for (int n = wid; n < N; n += nw) {
    float u1 = 0.0f, s1 = 0.0f, v2 = 0.0f, s2 = 0.0f;
    {  // out-direction: u1 += ii[c]*xr[c], s1 += ii[c]*xi[c]
      int lo = n ? ofs_out[n - 1] : 0, hi = ofs_out[n];
      int j = lo;
      for (; j + 4 <= hi; j += 4) {
        uint i0 = idx_out[j], i1 = idx_out[j + 1], i2 = idx_out[j + 2], i3 = idx_out[j + 3];
        uint p0 = xin_p[(size_t)i0 * D + lane];
        uint p1 = xin_p[(size_t)i1 * D + lane];
        uint p2 = xin_p[(size_t)i2 * D + lane];
        uint p3 = xin_p[(size_t)i3 * D + lane];
        float2 a0 = h2_to_f2(p0), a1 = h2_to_f2(p1), a2 = h2_to_f2(p2), a3 = h2_to_f2(p3);
        u1 += (a0.x + a1.x) + (a2.x + a3.x);
        s1 += (a0.y + a1.y) + (a2.y + a3.y);
      }
      for (; j < hi; ++j) {
        float2 a0 = h2_to_f2(xin_p[(size_t)idx_out[j] * D + lane]);
        u1 += a0.x;
        s1 += a0.y;
      }
    }
    {  // in-direction: v2 += io[r]*xr[r], s2 += io[r]*xi[r]
      int lo = n ? ofs_in[n - 1] : 0, hi = ofs_in[n];
      int j = lo;
      for (; j + 4 <= hi; j += 4) {
        uint i0 = idx_in[j], i1 = idx_in[j + 1], i2 = idx_in[j + 2], i3 = idx_in[j + 3];
        uint p0 = xout_p[(size_t)i0 * D + lane];
        uint p1 = xout_p[(size_t)i1 * D + lane];
        uint p2 = xout_p[(size_t)i2 * D + lane];
        uint p3 = xout_p[(size_t)i3 * D + lane];
        float2 a0 = h2_to_f2(p0), a1 = h2_to_f2(p1), a2 = h2_to_f2(p2), a3 = h2_to_f2(p3);
        v2 += (a0.x + a1.x) + (a2.x + a3.x);
        s2 += (a0.y + a1.y) + (a2.y + a3.y);
      }
      for (; j < hi; ++j) {
        float2 a0 = h2_to_f2(xout_p[(size_t)idx_in[j] * D + lane]);
        v2 += a0.x;
        s2 += a0.y;
      }
    }
    float io = inv_out[n], ii = inv_in[n];
    float u = io * u1, v = ii * v2, s = io * s1 + ii * s2;
    // epilogue: accR = cR + sum_d p*wr - sh*wi ; accI = cI + sh*wr + u*wi
    mv[lane] = make_float4(0.5f * (u + v), 0.5f * s, u, 0.0f);
    // wave-synchronous LDS RAW (same-wave DS ops ordered via lgkmcnt)
    float accR = cRv, accI = cIv;
#pragma unroll 4
    for (int d = 0; d < 64; ++d) {
      float4 pv = mv[d];                     // b128 broadcast
      float2 w2 = h2_to_f2(sW[d * 64 + lane]);  // b32, 2-way alias (free)
      accR += pv.x * w2.x - pv.y * w2.y;
      accI += pv.y * w2.x + pv.z * w2.y;
    }
    out_real[(size_t)n * D + lane] = accR;
    out_imag[(size_t)n * D + lane] = accI;
  }
}

extern "C" void kernel_launch(void* const* d_in, const int* in_sizes, int n_in,
                              void* d_out, int out_size, void* d_ws, size_t ws_size,
                              hipStream_t stream) {
  const float* x_real = (const float*)d_in[0];
  const float* x_imag = (const float*)d_in[1];
  const int* edge = (const int*)d_in[2];
  const float* W_real = (const float*)d_in[3];
  const float* b_real = (const float*)d_in[4];
  const float* W_imag = (const float*)d_in[5];
  const float* b_imag = (const float*)d_in[6];

  const int N = in_sizes[0] / D;  // 100000
  const int E = in_sizes[2] / 2;  // 1600000
  const int* row = edge;
  const int* col = edge + E;

  // workspace layout
  uint* idx_out  = (uint*)d_ws;               // E
  uint* idx_in   = idx_out + E;               // E
  uint* xout_p   = idx_in + E;                // N*64
  uint* xin_p    = xout_p + (size_t)N * D;    // N*64
  int* deg_out   = (int*)(xin_p + (size_t)N * D);  // N -- zeroed
  int* deg_in    = deg_out + N;               // N -- zeroed
  int* ofs_out   = deg_in + N;                // N
  int* ofs_in    = ofs_out + N;               // N
  float* inv_out = (float*)(ofs_in + N);      // N
  float* inv_in  = inv_out + N;               // N
  uint* Wh       = (uint*)(inv_in + N);       // 4096
  float* cR      = (float*)(Wh + 4096);       // 64
  float* cI      = cR + 64;                   // 64

  float* out_real = (float*)d_out;
  float* out_imag = out_real + (size_t)N * D;

  hipMemsetAsync(deg_out, 0, (size_t)2 * N * sizeof(int), stream);

  degree_kernel<<<(E + 255) / 256, 256, 0, stream>>>(row, col, deg_out, deg_in, E);
  scan_kernel<<<2, 1024, 0, stream>>>(deg_out, deg_in, ofs_out, ofs_in, inv_out, inv_in, N);
  pack_kernel<<<(N * D + 255) / 256, 256, 0, stream>>>(x_real, x_imag, inv_out, inv_in,
                                                       xout_p, xin_p, N * D);
  weights_kernel<<<16, 256, 0, stream>>>(W_real, b_real, W_imag, b_imag, Wh, cR, cI);
  fill_kernel<<<(E + 255) / 256, 256, 0, stream>>>(row, col, ofs_out, ofs_in,
                                                   idx_out, idx_in, E);
  gather_kernel<<<4096, 256, 0, stream>>>(xout_p, xin_p, idx_out, idx_in, ofs_out, ofs_in,
                                          inv_out, inv_in, Wh, cR, cI,
                                          out_real, out_imag, N);
}

// Round 4
// 898.431 us; speedup vs baseline: 1.8345x; 1.0646x over previous
//
#include <hip/hip_runtime.h>
#include <hip/hip_fp16.h>

// ComplexFaberConv: degree-normalized directed SpMM + collapsed complex linear.
//
// Math (linear in k, so W-stacks collapse):
//   WrE = sum_k 0.5^k W_real[k], WiE likewise; brE, biE likewise.
//   u = y_real, v = y_real_t, S = y_imag + y_imag_t
//   total_real = 0.5*(u+v)@WrE^T - 0.5*S@WiE^T + (brE-biE)
//   total_imag = u@WiE^T + 0.5*S@WrE^T + (brE+biE)
// (reference faithfully uses y_real, not y_real_t, in sum_imag_d2s)
//
// R4: (a) fill was 64B-line write-amplification bound (WRITE_SIZE 202MB =
// 3.2M stores x 64B). Multi-pass windowed fill: edges in registers, 8 passes
// over 12.5K-node ranges -> contiguous ~1.6MB L2-resident write window.
// (b) gather: uint4 lane layout, 4 edges/wave/instruction, unroll 2.

constexpr int D = 64;
constexpr int NPASS = 8;
constexpr int FILL_K = 4;

__device__ __forceinline__ float2 h2_to_f2(uint p) {
  __half2 h = *(__half2*)&p;
  return __half22float2(h);
}

__global__ void degree_kernel(const int* __restrict__ row, const int* __restrict__ col,
                              int* __restrict__ deg_out, int* __restrict__ deg_in, int E) {
  int e = blockIdx.x * blockDim.x + threadIdx.x;
  if (e < E) {
    atomicAdd(&deg_out[row[e]], 1);
    atomicAdd(&deg_in[col[e]], 1);
  }
}

// One block per array (grid.x = 2): exclusive scan of degrees -> ofs,
// plus inv[i] = deg^-0.25 (0 if deg==0).
__global__ __launch_bounds__(1024) void scan_kernel(
    const int* __restrict__ deg_out, const int* __restrict__ deg_in,
    int* __restrict__ ofs_out, int* __restrict__ ofs_in,
    float* __restrict__ inv_out, float* __restrict__ inv_in, int N) {
  const int* deg = blockIdx.x ? deg_in : deg_out;
  int* ofs = blockIdx.x ? ofs_in : ofs_out;
  float* inv = blockIdx.x ? inv_in : inv_out;
  __shared__ int ps[1024];
  int t = threadIdx.x;
  int chunk = (N + 1023) >> 10;
  int b = t * chunk, e = min(N, b + chunk);
  int s = 0;
  for (int i = b; i < e; ++i) {
    int d = deg[i];
    s += d;
    inv[i] = d > 0 ? rsqrtf(sqrtf((float)d)) : 0.0f;
  }
  ps[t] = s;
  __syncthreads();
  for (int off = 1; off < 1024; off <<= 1) {  // inclusive Hillis-Steele
    int v = (t >= off) ? ps[t - off] : 0;
    __syncthreads();
    ps[t] += v;
    __syncthreads();
  }
  int run = ps[t] - s;  // exclusive prefix
  for (int i = b; i < e; ++i) {
    ofs[i] = run;
    run += deg[i];
  }
}

// Pre-scaled packed features (vectorized: 4 features/thread):
//   xin_p[n*64+d]  = half2(inv_in[n]*xr,  inv_in[n]*xi)   (gathered by out-dir)
//   xout_p[n*64+d] = half2(inv_out[n]*xr, inv_out[n]*xi)  (gathered by in-dir)
__global__ void pack_kernel(const float* __restrict__ xr, const float* __restrict__ xi,
                            const float* __restrict__ inv_out, const float* __restrict__ inv_in,
                            uint* __restrict__ xout_p, uint* __restrict__ xin_p, int total4) {
  int i = blockIdx.x * blockDim.x + threadIdx.x;  // over N*16 uint4 groups
  if (i < total4) {
    int n = i >> 4;
    float4 a = ((const float4*)xr)[i];
    float4 b = ((const float4*)xi)[i];
    float io = inv_out[n], ii = inv_in[n];
    __half2 h;
    uint4 o, p;
    h = __floats2half2_rn(io * a.x, io * b.x); o.x = *(uint*)&h;
    h = __floats2half2_rn(io * a.y, io * b.y); o.y = *(uint*)&h;
    h = __floats2half2_rn(io * a.z, io * b.z); o.z = *(uint*)&h;
    h = __floats2half2_rn(io * a.w, io * b.w); o.w = *(uint*)&h;
    h = __floats2half2_rn(ii * a.x, ii * b.x); p.x = *(uint*)&h;
    h = __floats2half2_rn(ii * a.y, ii * b.y); p.y = *(uint*)&h;
    h = __floats2half2_rn(ii * a.z, ii * b.z); p.z = *(uint*)&h;
    h = __floats2half2_rn(ii * a.w, ii * b.w); p.w = *(uint*)&h;
    ((uint4*)xout_p)[i] = o;
    ((uint4*)xin_p)[i] = p;
  }
}

// Multi-pass windowed CSR fill. Edges preloaded to registers; pass p only
// writes buckets for nodes in [p*PS, (p+1)*PS) -> contiguous L2-resident
// window of the idx arrays (CSR offsets are monotone in node id).
// ofs arrays double as cursors (after fill, ofs[n] = end of bucket n).
__global__ void fill_kernel(const int* __restrict__ row, const int* __restrict__ col,
                            int* __restrict__ ofs_out, int* __restrict__ ofs_in,
                            uint* __restrict__ idx_out, uint* __restrict__ idx_in,
                            int E, int PS) {
  int tid = blockIdx.x * blockDim.x + threadIdx.x;
  int T = gridDim.x * blockDim.x;
  int r[FILL_K], c[FILL_K];
#pragma unroll
  for (int k = 0; k < FILL_K; ++k) {
    int e = tid + k * T;
    if (e < E) { r[k] = row[e]; c[k] = col[e]; } else { r[k] = -1; c[k] = -1; }
  }
  for (int p = 0; p < NPASS; ++p) {
    int lo = p * PS, hi = lo + PS;
#pragma unroll
    for (int k = 0; k < FILL_K; ++k) {
      if (r[k] >= lo && r[k] < hi) idx_out[atomicAdd(&ofs_out[r[k]], 1)] = (uint)c[k];
      if (c[k] >= lo && c[k] < hi) idx_in[atomicAdd(&ofs_in[c[k]], 1)] = (uint)r[k];
    }
  }
}

// Collapse K=3 weight stacks; pack (wr,wi) as half2: Wh[d*64+o].
__global__ void weights_kernel(const float* __restrict__ Wr, const float* __restrict__ br,
                               const float* __restrict__ Wi, const float* __restrict__ bi,
                               uint* __restrict__ Wh, float* __restrict__ cR,
                               float* __restrict__ cI) {
  int i = blockIdx.x * blockDim.x + threadIdx.x;  // 0..4095 -> (o,d)
  if (i < 4096) {
    int o = i >> 6, d = i & 63;
    float wr = Wr[i] + 0.5f * Wr[4096 + i] + 0.25f * Wr[8192 + i];
    float wi = Wi[i] + 0.5f * Wi[4096 + i] + 0.25f * Wi[8192 + i];
    __half2 h = __floats2half2_rn(wr, wi);
    Wh[d * 64 + o] = *(uint*)&h;
    if (i < 64) {
      float brv = br[i] + 0.5f * br[64 + i] + 0.25f * br[128 + i];
      float biv = bi[i] + 0.5f * bi[64 + i] + 0.25f * bi[128 + i];
      cR[i] = brv - biv;
      cI[i] = brv + biv;
    }
  }
}

// One wave per node. Lane l handles features 4*(l&15)..+3 of edge j+(l>>4):
// one dwordx4 gather covers 4 edges per wave-instruction; unroll 2 -> 8 edges
// in flight. Cross-subgroup shfl_xor(16,32) reduction, then fused complex
// linear epilogue (half2 weights in LDS).
__global__ __launch_bounds__(256) void gather_kernel(
    const uint4* __restrict__ xout4, const uint4* __restrict__ xin4,
    const uint* __restrict__ idx_out, const uint* __restrict__ idx_in,
    const int* __restrict__ ofs_out, const int* __restrict__ ofs_in,
    const float* __restrict__ inv_out, const float* __restrict__ inv_in,
    const uint* __restrict__ Wh, const float* __restrict__ cR, const float* __restrict__ cI,
    float* __restrict__ out_real, float* __restrict__ out_imag, int N) {
  __shared__ uint sW[4096];     // 16 KB half2 weights
  __shared__ float4 sV[4][64];  // 4 KB per-wave staging
  for (int i = threadIdx.x; i < 4096; i += 256) sW[i] = Wh[i];
  __syncthreads();
  int wv = __builtin_amdgcn_readfirstlane(threadIdx.x >> 6);
  int lane = threadIdx.x & 63;
  int sub = lane >> 4;     // edge slot 0..3
  int q = lane & 15;       // uint4 slot -> features 4q..4q+3
  float cRv = cR[lane], cIv = cI[lane];
  float4* mv = &sV[wv][0];
  int wid = blockIdx.x * 4 + wv;
  int nw = gridDim.x * 4;
  for (int n = wid; n < N; n += nw) {
    float4 u1 = {0, 0, 0, 0}, s1 = {0, 0, 0, 0};
    float4 v2 = {0, 0, 0, 0}, s2 = {0, 0, 0, 0};
#define ACC(P, U, S)                                          \
  {                                                           \
    float2 a0 = h2_to_f2((P).x), a1 = h2_to_f2((P).y);        \
    float2 a2 = h2_to_f2((P).z), a3 = h2_to_f2((P).w);        \
    U.x += a0.x; S.x += a0.y; U.y += a1.x; S.y += a1.y;       \
    U.z += a2.x; S.z += a2.y; U.w += a3.x; S.w += a3.y;       \
  }
    {  // out-direction: gathers xin4 (pre-scaled by inv_in of neighbor)
      int lo = n ? ofs_out[n - 1] : 0, hi = ofs_out[n];
      int len8 = (hi - lo) & ~7;
      int j = lo;
      for (; j < lo + len8; j += 8) {
        uint4 p0 = xin4[(size_t)idx_out[j + sub] * 16 + q];
        uint4 p1 = xin4[(size_t)idx_out[j + 4 + sub] * 16 + q];
        ACC(p0, u1, s1);
        ACC(p1, u1, s1);
      }
      for (; j < hi; j += 4) {
        if (j + sub < hi) {
          uint4 p0 = xin4[(size_t)idx_out[j + sub] * 16 + q];
          ACC(p0, u1, s1);
        }
      }
    }
    {  // in-direction: gathers xout4 (pre-scaled by inv_out of neighbor)
      int lo = n ? ofs_in[n - 1] : 0, hi = ofs_in[n];
      int len8 = (hi - lo) & ~7;
      int j = lo;
      for (; j < lo + len8; j += 8) {
        uint4 p0 = xout4[(size_t)idx_in[j + sub] * 16 + q];
        uint4 p1 = xout4[(size_t)idx_in[j + 4 + sub] * 16 + q];
        ACC(p0, v2, s2);
        ACC(p1, v2, s2);
      }
      for (; j < hi; j += 4) {
        if (j + sub < hi) {
          uint4 p0 = xout4[(size_t)idx_in[j + sub] * 16 + q];
          ACC(p0, v2, s2);
        }
      }
    }
#undef ACC
    // reduce the 4 edge-subgroups (lanes l, l^16, l^32, l^48)
#pragma unroll
    for (int m = 16; m < 64; m <<= 1) {
      u1.x += __shfl_xor(u1.x, m); u1.y += __shfl_xor(u1.y, m);
      u1.z += __shfl_xor(u1.z, m); u1.w += __shfl_xor(u1.w, m);
      s1.x += __shfl_xor(s1.x, m); s1.y += __shfl_xor(s1.y, m);
      s1.z += __shfl_xor(s1.z, m); s1.w += __shfl_xor(s1.w, m);
      v2.x += __shfl_xor(v2.x, m); v2.y += __shfl_xor(v2.y, m);
      v2.z += __shfl_xor(v2.z, m); v2.w += __shfl_xor(v2.w, m);
      s2.x += __shfl_xor(s2.x, m); s2.y += __shfl_xor(s2.y, m);
      s2.z += __shfl_xor(s2.z, m); s2.w += __shfl_xor(s2.w, m);
    }
    float io = inv_out[n], ii = inv_in[n];
    if (sub == 0) {  // stage features 4q..4q+3 -> {p, sh, u}
      float4 uu = {io * u1.x, io * u1.y, io * u1.z, io * u1.w};
      float4 vv = {ii * v2.x, ii * v2.y, ii * v2.z, ii * v2.w};
      float4 ss = {io * s1.x + ii * s2.x, io * s1.y + ii * s2.y,
                   io * s1.z + ii * s2.z, io * s1.w + ii * s2.w};
      mv[4 * q + 0] = make_float4(0.5f * (uu.x + vv.x), 0.5f * ss.x, uu.x, 0.0f);
      mv[4 * q + 1] = make_float4(0.5f * (uu.y + vv.y), 0.5f * ss.y, uu.y, 0.0f);
      mv[4 * q + 2] = make_float4(0.5f * (uu.z + vv.z), 0.5f * ss.z, uu.z, 0.0f);
      mv[4 * q + 3] = make_float4(0.5f * (uu.w + vv.w), 0.5f * ss.w, uu.w, 0.0f);
    }
    // wave-synchronous LDS RAW (same-wave DS ops ordered via lgkmcnt)
    float accR = cRv, accI = cIv;
#pragma unroll 4
    for (int d = 0; d < 64; ++d) {
      float4 pv = mv[d];                        // b128 broadcast
      float2 w2 = h2_to_f2(sW[d * 64 + lane]);  // b32, 2-way alias (free)
      accR += pv.x * w2.x - pv.y * w2.y;
      accI += pv.y * w2.x + pv.z * w2.y;
    }
    out_real[(size_t)n * D + lane] = accR;
    out_imag[(size_t)n * D + lane] = accI;
  }
}

extern "C" void kernel_launch(void* const* d_in, const int* in_sizes, int n_in,
                              void* d_out, int out_size, void* d_ws, size_t ws_size,
                              hipStream_t stream) {
  const float* x_real = (const float*)d_in[0];
  const float* x_imag = (const float*)d_in[1];
  const int* edge = (const int*)d_in[2];
  const float* W_real = (const float*)d_in[3];
  const float* b_real = (const float*)d_in[4];
  const float* W_imag = (const float*)d_in[5];
  const float* b_imag = (const float*)d_in[6];

  const int N = in_sizes[0] / D;  // 100000
  const int E = in_sizes[2] / 2;  // 1600000
  const int* row = edge;
  const int* col = edge + E;

  // workspace layout (16B-aligned packed arrays first)
  uint* xout_p   = (uint*)d_ws;                    // N*64
  uint* xin_p    = xout_p + (size_t)N * D;         // N*64
  uint* idx_out  = xin_p + (size_t)N * D;          // E
  uint* idx_in   = idx_out + E;                    // E
  int* deg_out   = (int*)(idx_in + E);             // N -- zeroed
  int* deg_in    = deg_out + N;                    // N -- zeroed
  int* ofs_out   = deg_in + N;                     // N
  int* ofs_in    = ofs_out + N;                    // N
  float* inv_out = (float*)(ofs_in + N);           // N
  float* inv_in  = inv_out + N;                    // N
  uint* Wh       = (uint*)(inv_in + N);            // 4096
  float* cR      = (float*)(Wh + 4096);            // 64
  float* cI      = cR + 64;                        // 64

  float* out_real = (float*)d_out;
  float* out_imag = out_real + (size_t)N * D;

  hipMemsetAsync(deg_out, 0, (size_t)2 * N * sizeof(int), stream);

  degree_kernel<<<(E + 255) / 256, 256, 0, stream>>>(row, col, deg_out, deg_in, E);
  scan_kernel<<<2, 1024, 0, stream>>>(deg_out, deg_in, ofs_out, ofs_in, inv_out, inv_in, N);
  pack_kernel<<<(N * 16 + 255) / 256, 256, 0, stream>>>(x_real, x_imag, inv_out, inv_in,
                                                        xout_p, xin_p, N * 16);
  weights_kernel<<<16, 256, 0, stream>>>(W_real, b_real, W_imag, b_imag, Wh, cR, cI);
  int fill_blocks = (E + FILL_K * 256 - 1) / (FILL_K * 256);
  int PS = (N + NPASS - 1) / NPASS;
  fill_kernel<<<fill_blocks, 256, 0, stream>>>(row, col, ofs_out, ofs_in,
                                               idx_out, idx_in, E, PS);
  gather_kernel<<<4096, 256, 0, stream>>>((const uint4*)xout_p, (const uint4*)xin_p,
                                          idx_out, idx_in, ofs_out, ofs_in,
                                          inv_out, inv_in, Wh, cR, cI,
                                          out_real, out_imag, N);
}

// Round 5
// 630.408 us; speedup vs baseline: 2.6145x; 1.4252x over previous
//
#include <hip/hip_runtime.h>
#include <hip/hip_fp16.h>

// ComplexFaberConv: degree-normalized directed SpMM + collapsed complex linear.
//
// Math (linear in k, so W-stacks collapse):
//   WrE = sum_k 0.5^k W_real[k], WiE likewise; brE, biE likewise.
//   u = y_real, v = y_real_t, S = y_imag + y_imag_t
//   total_real = 0.5*(u+v)@WrE^T - 0.5*S@WiE^T + (brE-biE)
//   total_imag = u@WiE^T + 0.5*S@WrE^T + (brE+biE)
// (reference faithfully uses y_real, not y_real_t, in sum_imag_d2s)
//
// R5: the 2-block scan_kernel was the hidden #1 (283us, occupancy 0.33% --
// 254 CUs idle). Replaced with 3-phase multi-block scan (block sums ->
// single-block scan of sums -> final scan+write). Fill/gather unchanged.

constexpr int D = 64;
constexpr int NPASS = 8;
constexpr int FILL_K = 4;
constexpr int SB = 256;  // scan elements per block

__device__ __forceinline__ float2 h2_to_f2(uint p) {
  __half2 h = *(__half2*)&p;
  return __half22float2(h);
}

__global__ void degree_kernel(const int* __restrict__ row, const int* __restrict__ col,
                              int* __restrict__ deg_out, int* __restrict__ deg_in, int E) {
  int e = blockIdx.x * blockDim.x + threadIdx.x;
  if (e < E) {
    atomicAdd(&deg_out[row[e]], 1);
    atomicAdd(&deg_in[col[e]], 1);
  }
}

// Phase 1: per-block degree sums. grid = (NB, 2); y selects array.
__global__ __launch_bounds__(SB) void bsum_kernel(
    const int* __restrict__ deg_out, const int* __restrict__ deg_in,
    int* __restrict__ bsum, int N, int NB) {
  const int* deg = blockIdx.y ? deg_in : deg_out;
  int i = blockIdx.x * SB + threadIdx.x;
  int d = (i < N) ? deg[i] : 0;
#pragma unroll
  for (int m = 1; m < 64; m <<= 1) d += __shfl_xor(d, m);
  __shared__ int ws[SB / 64];
  if ((threadIdx.x & 63) == 0) ws[threadIdx.x >> 6] = d;
  __syncthreads();
  if (threadIdx.x == 0) {
    int s = 0;
#pragma unroll
    for (int w = 0; w < SB / 64; ++w) s += ws[w];
    bsum[blockIdx.y * NB + blockIdx.x] = s;
  }
}

// Phase 2: exclusive scan of both block-sum segments (NB <= 1024 each),
// one block of 1024 threads, both segments scanned in the same LDS pass.
__global__ __launch_bounds__(1024) void bscan_kernel(int* __restrict__ bsum, int NB) {
  __shared__ int s0[1024], s1[1024];
  int t = threadIdx.x;
  int o0 = (t < NB) ? bsum[t] : 0;
  int o1 = (t < NB) ? bsum[NB + t] : 0;
  s0[t] = o0;
  s1[t] = o1;
  __syncthreads();
  for (int off = 1; off < 1024; off <<= 1) {
    int v0 = (t >= off) ? s0[t - off] : 0;
    int v1 = (t >= off) ? s1[t - off] : 0;
    __syncthreads();
    s0[t] += v0;
    s1[t] += v1;
    __syncthreads();
  }
  if (t < NB) {
    bsum[t] = s0[t] - o0;            // exclusive
    bsum[NB + t] = s1[t] - o1;
  }
}

// Phase 3: in-block exclusive scan + block base -> ofs (exclusive prefix),
// plus inv = deg^-0.25 (0 if deg==0). grid = (NB, 2).
__global__ __launch_bounds__(SB) void sfin_kernel(
    const int* __restrict__ deg_out, const int* __restrict__ deg_in,
    const int* __restrict__ bsum,
    int* __restrict__ ofs_out, int* __restrict__ ofs_in,
    float* __restrict__ inv_out, float* __restrict__ inv_in, int N, int NB) {
  const int* deg = blockIdx.y ? deg_in : deg_out;
  int* ofs = blockIdx.y ? ofs_in : ofs_out;
  float* inv = blockIdx.y ? inv_in : inv_out;
  int base = bsum[blockIdx.y * NB + blockIdx.x];
  int lane = threadIdx.x & 63, wv = threadIdx.x >> 6;
  int i = blockIdx.x * SB + threadIdx.x;
  int d = (i < N) ? deg[i] : 0;
  int sc = d;  // wave-level inclusive scan
#pragma unroll
  for (int off = 1; off < 64; off <<= 1) {
    int v = __shfl_up(sc, off);
    if (lane >= off) sc += v;
  }
  __shared__ int ws[SB / 64];
  if (lane == 63) ws[wv] = sc;
  __syncthreads();
  int wbase = 0;
#pragma unroll
  for (int w = 0; w < SB / 64; ++w)
    if (w < wv) wbase += ws[w];
  if (i < N) {
    ofs[i] = base + wbase + (sc - d);  // exclusive prefix
    inv[i] = d > 0 ? rsqrtf(sqrtf((float)d)) : 0.0f;
  }
}

// Pre-scaled packed features (vectorized: 4 features/thread):
//   xin_p[n*64+d]  = half2(inv_in[n]*xr,  inv_in[n]*xi)   (gathered by out-dir)
//   xout_p[n*64+d] = half2(inv_out[n]*xr, inv_out[n]*xi)  (gathered by in-dir)
__global__ void pack_kernel(const float* __restrict__ xr, const float* __restrict__ xi,
                            const float* __restrict__ inv_out, const float* __restrict__ inv_in,
                            uint* __restrict__ xout_p, uint* __restrict__ xin_p, int total4) {
  int i = blockIdx.x * blockDim.x + threadIdx.x;  // over N*16 uint4 groups
  if (i < total4) {
    int n = i >> 4;
    float4 a = ((const float4*)xr)[i];
    float4 b = ((const float4*)xi)[i];
    float io = inv_out[n], ii = inv_in[n];
    __half2 h;
    uint4 o, p;
    h = __floats2half2_rn(io * a.x, io * b.x); o.x = *(uint*)&h;
    h = __floats2half2_rn(io * a.y, io * b.y); o.y = *(uint*)&h;
    h = __floats2half2_rn(io * a.z, io * b.z); o.z = *(uint*)&h;
    h = __floats2half2_rn(io * a.w, io * b.w); o.w = *(uint*)&h;
    h = __floats2half2_rn(ii * a.x, ii * b.x); p.x = *(uint*)&h;
    h = __floats2half2_rn(ii * a.y, ii * b.y); p.y = *(uint*)&h;
    h = __floats2half2_rn(ii * a.z, ii * b.z); p.z = *(uint*)&h;
    h = __floats2half2_rn(ii * a.w, ii * b.w); p.w = *(uint*)&h;
    ((uint4*)xout_p)[i] = o;
    ((uint4*)xin_p)[i] = p;
  }
}

// Multi-pass windowed CSR fill. Edges preloaded to registers; pass p only
// writes buckets for nodes in [p*PS, (p+1)*PS) -> contiguous L2-resident
// window of the idx arrays (CSR offsets are monotone in node id).
// ofs arrays double as cursors (after fill, ofs[n] = end of bucket n).
__global__ void fill_kernel(const int* __restrict__ row, const int* __restrict__ col,
                            int* __restrict__ ofs_out, int* __restrict__ ofs_in,
                            uint* __restrict__ idx_out, uint* __restrict__ idx_in,
                            int E, int PS) {
  int tid = blockIdx.x * blockDim.x + threadIdx.x;
  int T = gridDim.x * blockDim.x;
  int r[FILL_K], c[FILL_K];
#pragma unroll
  for (int k = 0; k < FILL_K; ++k) {
    int e = tid + k * T;
    if (e < E) { r[k] = row[e]; c[k] = col[e]; } else { r[k] = -1; c[k] = -1; }
  }
  for (int p = 0; p < NPASS; ++p) {
    int lo = p * PS, hi = lo + PS;
#pragma unroll
    for (int k = 0; k < FILL_K; ++k) {
      if (r[k] >= lo && r[k] < hi) idx_out[atomicAdd(&ofs_out[r[k]], 1)] = (uint)c[k];
      if (c[k] >= lo && c[k] < hi) idx_in[atomicAdd(&ofs_in[c[k]], 1)] = (uint)r[k];
    }
  }
}

// Collapse K=3 weight stacks; pack (wr,wi) as half2: Wh[d*64+o].
__global__ void weights_kernel(const float* __restrict__ Wr, const float* __restrict__ br,
                               const float* __restrict__ Wi, const float* __restrict__ bi,
                               uint* __restrict__ Wh, float* __restrict__ cR,
                               float* __restrict__ cI) {
  int i = blockIdx.x * blockDim.x + threadIdx.x;  // 0..4095 -> (o,d)
  if (i < 4096) {
    int o = i >> 6, d = i & 63;
    float wr = Wr[i] + 0.5f * Wr[4096 + i] + 0.25f * Wr[8192 + i];
    float wi = Wi[i] + 0.5f * Wi[4096 + i] + 0.25f * Wi[8192 + i];
    __half2 h = __floats2half2_rn(wr, wi);
    Wh[d * 64 + o] = *(uint*)&h;
    if (i < 64) {
      float brv = br[i] + 0.5f * br[64 + i] + 0.25f * br[128 + i];
      float biv = bi[i] + 0.5f * bi[64 + i] + 0.25f * bi[128 + i];
      cR[i] = brv - biv;
      cI[i] = brv + biv;
    }
  }
}

// One wave per node. Lane l handles features 4*(l&15)..+3 of edge j+(l>>4):
// one dwordx4 gather covers 4 edges per wave-instruction; unroll 2 -> 8 edges
// in flight. Cross-subgroup shfl_xor(16,32) reduction, then fused complex
// linear epilogue (half2 weights in LDS).
__global__ __launch_bounds__(256) void gather_kernel(
    const uint4* __restrict__ xout4, const uint4* __restrict__ xin4,
    const uint* __restrict__ idx_out, const uint* __restrict__ idx_in,
    const int* __restrict__ ofs_out, const int* __restrict__ ofs_in,
    const float* __restrict__ inv_out, const float* __restrict__ inv_in,
    const uint* __restrict__ Wh, const float* __restrict__ cR, const float* __restrict__ cI,
    float* __restrict__ out_real, float* __restrict__ out_imag, int N) {
  __shared__ uint sW[4096];     // 16 KB half2 weights
  __shared__ float4 sV[4][64];  // 4 KB per-wave staging
  for (int i = threadIdx.x; i < 4096; i += 256) sW[i] = Wh[i];
  __syncthreads();
  int wv = __builtin_amdgcn_readfirstlane(threadIdx.x >> 6);
  int lane = threadIdx.x & 63;
  int sub = lane >> 4;     // edge slot 0..3
  int q = lane & 15;       // uint4 slot -> features 4q..4q+3
  float cRv = cR[lane], cIv = cI[lane];
  float4* mv = &sV[wv][0];
  int wid = blockIdx.x * 4 + wv;
  int nw = gridDim.x * 4;
  for (int n = wid; n < N; n += nw) {
    float4 u1 = {0, 0, 0, 0}, s1 = {0, 0, 0, 0};
    float4 v2 = {0, 0, 0, 0}, s2 = {0, 0, 0, 0};
#define ACC(P, U, S)                                          \
  {                                                           \
    float2 a0 = h2_to_f2((P).x), a1 = h2_to_f2((P).y);        \
    float2 a2 = h2_to_f2((P).z), a3 = h2_to_f2((P).w);        \
    U.x += a0.x; S.x += a0.y; U.y += a1.x; S.y += a1.y;       \
    U.z += a2.x; S.z += a2.y; U.w += a3.x; S.w += a3.y;       \
  }
    {  // out-direction: gathers xin4 (pre-scaled by inv_in of neighbor)
      int lo = n ? ofs_out[n - 1] : 0, hi = ofs_out[n];
      int len8 = (hi - lo) & ~7;
      int j = lo;
      for (; j < lo + len8; j += 8) {
        uint4 p0 = xin4[(size_t)idx_out[j + sub] * 16 + q];
        uint4 p1 = xin4[(size_t)idx_out[j + 4 + sub] * 16 + q];
        ACC(p0, u1, s1);
        ACC(p1, u1, s1);
      }
      for (; j < hi; j += 4) {
        if (j + sub < hi) {
          uint4 p0 = xin4[(size_t)idx_out[j + sub] * 16 + q];
          ACC(p0, u1, s1);
        }
      }
    }
    {  // in-direction: gathers xout4 (pre-scaled by inv_out of neighbor)
      int lo = n ? ofs_in[n - 1] : 0, hi = ofs_in[n];
      int len8 = (hi - lo) & ~7;
      int j = lo;
      for (; j < lo + len8; j += 8) {
        uint4 p0 = xout4[(size_t)idx_in[j + sub] * 16 + q];
        uint4 p1 = xout4[(size_t)idx_in[j + 4 + sub] * 16 + q];
        ACC(p0, v2, s2);
        ACC(p1, v2, s2);
      }
      for (; j < hi; j += 4) {
        if (j + sub < hi) {
          uint4 p0 = xout4[(size_t)idx_in[j + sub] * 16 + q];
          ACC(p0, v2, s2);
        }
      }
    }
#undef ACC
    // reduce the 4 edge-subgroups (lanes l, l^16, l^32, l^48)
#pragma unroll
    for (int m = 16; m < 64; m <<= 1) {
      u1.x += __shfl_xor(u1.x, m); u1.y += __shfl_xor(u1.y, m);
      u1.z += __shfl_xor(u1.z, m); u1.w += __shfl_xor(u1.w, m);
      s1.x += __shfl_xor(s1.x, m); s1.y += __shfl_xor(s1.y, m);
      s1.z += __shfl_xor(s1.z, m); s1.w += __shfl_xor(s1.w, m);
      v2.x += __shfl_xor(v2.x, m); v2.y += __shfl_xor(v2.y, m);
      v2.z += __shfl_xor(v2.z, m); v2.w += __shfl_xor(v2.w, m);
      s2.x += __shfl_xor(s2.x, m); s2.y += __shfl_xor(s2.y, m);
      s2.z += __shfl_xor(s2.z, m); s2.w += __shfl_xor(s2.w, m);
    }
    float io = inv_out[n], ii = inv_in[n];
    if (sub == 0) {  // stage features 4q..4q+3 -> {p, sh, u}
      float4 uu = {io * u1.x, io * u1.y, io * u1.z, io * u1.w};
      float4 vv = {ii * v2.x, ii * v2.y, ii * v2.z, ii * v2.w};
      float4 ss = {io * s1.x + ii * s2.x, io * s1.y + ii * s2.y,
                   io * s1.z + ii * s2.z, io * s1.w + ii * s2.w};
      mv[4 * q + 0] = make_float4(0.5f * (uu.x + vv.x), 0.5f * ss.x, uu.x, 0.0f);
      mv[4 * q + 1] = make_float4(0.5f * (uu.y + vv.y), 0.5f * ss.y, uu.y, 0.0f);
      mv[4 * q + 2] = make_float4(0.5f * (uu.z + vv.z), 0.5f * ss.z, uu.z, 0.0f);
      mv[4 * q + 3] = make_float4(0.5f * (uu.w + vv.w), 0.5f * ss.w, uu.w, 0.0f);
    }
    // wave-synchronous LDS RAW (same-wave DS ops ordered via lgkmcnt)
    float accR = cRv, accI = cIv;
#pragma unroll 4
    for (int d = 0; d < 64; ++d) {
      float4 pv = mv[d];                        // b128 broadcast
      float2 w2 = h2_to_f2(sW[d * 64 + lane]);  // b32, 2-way alias (free)
      accR += pv.x * w2.x - pv.y * w2.y;
      accI += pv.y * w2.x + pv.z * w2.y;
    }
    out_real[(size_t)n * D + lane] = accR;
    out_imag[(size_t)n * D + lane] = accI;
  }
}

extern "C" void kernel_launch(void* const* d_in, const int* in_sizes, int n_in,
                              void* d_out, int out_size, void* d_ws, size_t ws_size,
                              hipStream_t stream) {
  const float* x_real = (const float*)d_in[0];
  const float* x_imag = (const float*)d_in[1];
  const int* edge = (const int*)d_in[2];
  const float* W_real = (const float*)d_in[3];
  const float* b_real = (const float*)d_in[4];
  const float* W_imag = (const float*)d_in[5];
  const float* b_imag = (const float*)d_in[6];

  const int N = in_sizes[0] / D;  // 100000
  const int E = in_sizes[2] / 2;  // 1600000
  const int* row = edge;
  const int* col = edge + E;
  const int NB = (N + SB - 1) / SB;  // scan blocks per array (391 <= 1024)

  // workspace layout (16B-aligned packed arrays first)
  uint* xout_p   = (uint*)d_ws;                    // N*64
  uint* xin_p    = xout_p + (size_t)N * D;         // N*64
  uint* idx_out  = xin_p + (size_t)N * D;          // E
  uint* idx_in   = idx_out + E;                    // E
  int* deg_out   = (int*)(idx_in + E);             // N -- zeroed
  int* deg_in    = deg_out + N;                    // N -- zeroed
  int* ofs_out   = deg_in + N;                     // N
  int* ofs_in    = ofs_out + N;                    // N
  float* inv_out = (float*)(ofs_in + N);           // N
  float* inv_in  = inv_out + N;                    // N
  uint* Wh       = (uint*)(inv_in + N);            // 4096
  float* cR      = (float*)(Wh + 4096);            // 64
  float* cI      = cR + 64;                        // 64
  int* bsum      = (int*)(cI + 64);                // 2*NB

  float* out_real = (float*)d_out;
  float* out_imag = out_real + (size_t)N * D;

  hipMemsetAsync(deg_out, 0, (size_t)2 * N * sizeof(int), stream);

  degree_kernel<<<(E + 255) / 256, 256, 0, stream>>>(row, col, deg_out, deg_in, E);
  bsum_kernel<<<dim3(NB, 2), SB, 0, stream>>>(deg_out, deg_in, bsum, N, NB);
  bscan_kernel<<<1, 1024, 0, stream>>>(bsum, NB);
  sfin_kernel<<<dim3(NB, 2), SB, 0, stream>>>(deg_out, deg_in, bsum, ofs_out, ofs_in,
                                              inv_out, inv_in, N, NB);
  pack_kernel<<<(N * 16 + 255) / 256, 256, 0, stream>>>(x_real, x_imag, inv_out, inv_in,
                                                        xout_p, xin_p, N * 16);
  weights_kernel<<<16, 256, 0, stream>>>(W_real, b_real, W_imag, b_imag, Wh, cR, cI);
  int fill_blocks = (E + FILL_K * 256 - 1) / (FILL_K * 256);
  int PS = (N + NPASS - 1) / NPASS;
  fill_kernel<<<fill_blocks, 256, 0, stream>>>(row, col, ofs_out, ofs_in,
                                               idx_out, idx_in, E, PS);
  gather_kernel<<<4096, 256, 0, stream>>>((const uint4*)xout_p, (const uint4*)xin_p,
                                          idx_out, idx_in, ofs_out, ofs_in,
                                          inv_out, inv_in, Wh, cR, cI,
                                          out_real, out_imag, N);
}

// Round 6
// 392.390 us; speedup vs baseline: 4.2004x; 1.6066x over previous
//
#include <hip/hip_runtime.h>
#include <hip/hip_fp16.h>

// ComplexFaberConv: degree-normalized directed SpMM + collapsed complex linear.
//
// Math (linear in k, so W-stacks collapse):
//   WrE = sum_k 0.5^k W_real[k], WiE likewise; brE, biE likewise.
//   u = y_real, v = y_real_t, S = y_imag + y_imag_t
//   total_real = 0.5*(u+v)@WrE^T - 0.5*S@WiE^T + (brE-biE)
//   total_imag = u@WiE^T + 0.5*S@WrE^T + (brE+biE)
// (reference faithfully uses y_real, not y_real_t, in sum_imag_d2s)
//
// R6: degree+fill chain (~380us hidden) was bound by cross-XCD false sharing
// on CSR lines (8 XCD L2s each dirtying the same 64B line). Rebuilt as
// bucket partition: 196 buckets of 512 nodes; per-(bucket,block) exclusive
// output ranges (no global atomics, no shared lines); per-bucket degree+fill
// with LDS histograms/cursors -- each output window owned by ONE block.

constexpr int D = 64;
constexpr int SB = 256;   // scan elements per block
constexpr int G1 = 256;   // partition blocks

__device__ __forceinline__ float2 h2_to_f2(uint p) {
  __half2 h = *(__half2*)&p;
  return __half22float2(h);
}

// ---------- partition phase ----------

// Per-block bucket histograms: h[bucket*G1 + block]. bucket = node>>9.
__global__ __launch_bounds__(256) void part_count(
    const int* __restrict__ row, const int* __restrict__ col,
    int* __restrict__ hout, int* __restrict__ hin, int E, int NBUK, int CH) {
  __shared__ int ho[256], hi_[256];
  int t = threadIdx.x, g = blockIdx.x;
  ho[t] = 0;
  hi_[t] = 0;
  __syncthreads();
  int e0 = g * CH, e1 = min(E, e0 + CH);
  for (int e = e0 + t; e < e1; e += 256) {
    atomicAdd(&ho[row[e] >> 9], 1);
    atomicAdd(&hi_[col[e] >> 9], 1);
  }
  __syncthreads();
  if (t < NBUK) {
    hout[t * G1 + g] = ho[t];
    hin[t * G1 + g] = hi_[t];
  }
}

// Scatter edges into block-exclusive per-bucket ranges (LDS cursors only).
// pack = (node_local<<17) | neighbor  (node_local<512 -> 9b, neighbor<131072 -> 17b)
__global__ __launch_bounds__(256) void part_scatter(
    const int* __restrict__ row, const int* __restrict__ col,
    const int* __restrict__ hout, const int* __restrict__ hin,
    uint* __restrict__ pout, uint* __restrict__ pin, int E, int NBUK, int CH) {
  __shared__ int co[256], ci[256];
  int t = threadIdx.x, g = blockIdx.x;
  if (t < NBUK) {
    co[t] = hout[t * G1 + g];
    ci[t] = hin[t * G1 + g];
  }
  __syncthreads();
  int e0 = g * CH, e1 = min(E, e0 + CH);
  for (int e = e0 + t; e < e1; e += 256) {
    int r = row[e], c = col[e];
    int po = atomicAdd(&co[r >> 9], 1);
    pout[po] = ((uint)(r & 511) << 17) | (uint)c;
    int pi = atomicAdd(&ci[c >> 9], 1);
    pin[pi] = ((uint)(c & 511) << 17) | (uint)r;
  }
}

// One block per bucket: LDS degree histogram -> coalesced global deg write.
__global__ __launch_bounds__(256) void bucket_degree(
    const uint* __restrict__ pout, const uint* __restrict__ pin,
    const int* __restrict__ hout, const int* __restrict__ hin,
    int* __restrict__ deg_out, int* __restrict__ deg_in, int E, int NBUK, int N) {
  const uint* p = blockIdx.y ? pin : pout;
  const int* h = blockIdx.y ? hin : hout;
  int* deg = blockIdx.y ? deg_in : deg_out;
  __shared__ int ld[512];
  int t = threadIdx.x, b = blockIdx.x;
  ld[t] = 0;
  ld[t + 256] = 0;
  __syncthreads();
  int s = h[b * G1];
  int e = (b + 1 < NBUK) ? h[(b + 1) * G1] : E;
  for (int j = s + t; j < e; j += 256) atomicAdd(&ld[p[j] >> 17], 1);
  __syncthreads();
  int n0 = (b << 9) + t;
  if (n0 < N) deg[n0] = ld[t];
  if (n0 + 256 < N) deg[n0 + 256] = ld[t + 256];
}

// One block per bucket: LDS cursors seeded from ofs; idx window (~32KB) is
// block-private -> single-XCD, no false sharing.
__global__ __launch_bounds__(256) void bucket_fill(
    const uint* __restrict__ pout, const uint* __restrict__ pin,
    const int* __restrict__ hout, const int* __restrict__ hin,
    const int* __restrict__ ofs_out, const int* __restrict__ ofs_in,
    uint* __restrict__ idx_out, uint* __restrict__ idx_in, int E, int NBUK, int N) {
  const uint* p = blockIdx.y ? pin : pout;
  const int* h = blockIdx.y ? hin : hout;
  const int* ofs = blockIdx.y ? ofs_in : ofs_out;
  uint* idx = blockIdx.y ? idx_in : idx_out;
  __shared__ int cur[512];
  int t = threadIdx.x, b = blockIdx.x;
  int n0 = (b << 9) + t;
  cur[t] = (n0 < N) ? ofs[n0] : 0;
  cur[t + 256] = (n0 + 256 < N) ? ofs[n0 + 256] : 0;
  __syncthreads();
  int s = h[b * G1];
  int e = (b + 1 < NBUK) ? h[(b + 1) * G1] : E;
  for (int j = s + t; j < e; j += 256) {
    uint pk = p[j];
    int pos = atomicAdd(&cur[pk >> 17], 1);
    idx[pos] = pk & 0x1FFFFu;
  }
}

// ---------- scans ----------

// Phase 1: per-block sums of two arrays. grid=(NB,2).
__global__ __launch_bounds__(SB) void bsum_kernel(
    const int* __restrict__ a0, const int* __restrict__ a1,
    int* __restrict__ bsum, int n, int NB) {
  const int* a = blockIdx.y ? a1 : a0;
  int i = blockIdx.x * SB + threadIdx.x;
  int d = (i < n) ? a[i] : 0;
#pragma unroll
  for (int m = 1; m < 64; m <<= 1) d += __shfl_xor(d, m);
  __shared__ int ws[SB / 64];
  if ((threadIdx.x & 63) == 0) ws[threadIdx.x >> 6] = d;
  __syncthreads();
  if (threadIdx.x == 0) {
    int s = 0;
#pragma unroll
    for (int w = 0; w < SB / 64; ++w) s += ws[w];
    bsum[blockIdx.y * NB + blockIdx.x] = s;
  }
}

// Phase 2: exclusive scan of both NB-entry segments (NB <= 1024), 1 block.
__global__ __launch_bounds__(1024) void bscan_kernel(int* __restrict__ bsum, int NB) {
  __shared__ int s0[1024], s1[1024];
  int t = threadIdx.x;
  int o0 = (t < NB) ? bsum[t] : 0;
  int o1 = (t < NB) ? bsum[NB + t] : 0;
  s0[t] = o0;
  s1[t] = o1;
  __syncthreads();
  for (int off = 1; off < 1024; off <<= 1) {
    int v0 = (t >= off) ? s0[t - off] : 0;
    int v1 = (t >= off) ? s1[t - off] : 0;
    __syncthreads();
    s0[t] += v0;
    s1[t] += v1;
    __syncthreads();
  }
  if (t < NB) {
    bsum[t] = s0[t] - o0;  // exclusive
    bsum[NB + t] = s1[t] - o1;
  }
}

// Phase 3 (generic, in-place): exclusive scan finalize for the histograms.
__global__ __launch_bounds__(SB) void gfin_kernel(
    int* __restrict__ h0, int* __restrict__ h1,
    const int* __restrict__ bsum, int n, int NB) {
  int* h = blockIdx.y ? h1 : h0;
  int base = bsum[blockIdx.y * NB + blockIdx.x];
  int lane = threadIdx.x & 63, wv = threadIdx.x >> 6;
  int i = blockIdx.x * SB + threadIdx.x;
  int d = (i < n) ? h[i] : 0;
  int sc = d;
#pragma unroll
  for (int off = 1; off < 64; off <<= 1) {
    int v = __shfl_up(sc, off);
    if (lane >= off) sc += v;
  }
  __shared__ int ws[SB / 64];
  if (lane == 63) ws[wv] = sc;
  __syncthreads();
  int wbase = 0;
#pragma unroll
  for (int w = 0; w < SB / 64; ++w)
    if (w < wv) wbase += ws[w];
  if (i < n) h[i] = base + wbase + (sc - d);
}

// Phase 3 (degrees): exclusive ofs (N+1, [N]=E) + inv = deg^-0.25.
__global__ __launch_bounds__(SB) void sfin_kernel(
    const int* __restrict__ deg_out, const int* __restrict__ deg_in,
    const int* __restrict__ bsum,
    int* __restrict__ ofs_out, int* __restrict__ ofs_in,
    float* __restrict__ inv_out, float* __restrict__ inv_in, int N, int NB) {
  const int* deg = blockIdx.y ? deg_in : deg_out;
  int* ofs = blockIdx.y ? ofs_in : ofs_out;
  float* inv = blockIdx.y ? inv_in : inv_out;
  int base = bsum[blockIdx.y * NB + blockIdx.x];
  int lane = threadIdx.x & 63, wv = threadIdx.x >> 6;
  int i = blockIdx.x * SB + threadIdx.x;
  int d = (i < N) ? deg[i] : 0;
  int sc = d;
#pragma unroll
  for (int off = 1; off < 64; off <<= 1) {
    int v = __shfl_up(sc, off);
    if (lane >= off) sc += v;
  }
  __shared__ int ws[SB / 64];
  if (lane == 63) ws[wv] = sc;
  __syncthreads();
  int wbase = 0;
#pragma unroll
  for (int w = 0; w < SB / 64; ++w)
    if (w < wv) wbase += ws[w];
  if (i < N) {
    ofs[i] = base + wbase + (sc - d);  // exclusive prefix
    inv[i] = d > 0 ? rsqrtf(sqrtf((float)d)) : 0.0f;
  }
  if (i == N - 1) ofs[N] = base + wbase + sc;
}

// ---------- dense prep ----------

// Pre-scaled packed features (4 features/thread):
//   xin_p[n*64+d]  = half2(inv_in[n]*xr,  inv_in[n]*xi)   (gathered by out-dir)
//   xout_p[n*64+d] = half2(inv_out[n]*xr, inv_out[n]*xi)  (gathered by in-dir)
__global__ void pack_kernel(const float* __restrict__ xr, const float* __restrict__ xi,
                            const float* __restrict__ inv_out, const float* __restrict__ inv_in,
                            uint* __restrict__ xout_p, uint* __restrict__ xin_p, int total4) {
  int i = blockIdx.x * blockDim.x + threadIdx.x;  // over N*16 uint4 groups
  if (i < total4) {
    int n = i >> 4;
    float4 a = ((const float4*)xr)[i];
    float4 b = ((const float4*)xi)[i];
    float io = inv_out[n], ii = inv_in[n];
    __half2 h;
    uint4 o, p;
    h = __floats2half2_rn(io * a.x, io * b.x); o.x = *(uint*)&h;
    h = __floats2half2_rn(io * a.y, io * b.y); o.y = *(uint*)&h;
    h = __floats2half2_rn(io * a.z, io * b.z); o.z = *(uint*)&h;
    h = __floats2half2_rn(io * a.w, io * b.w); o.w = *(uint*)&h;
    h = __floats2half2_rn(ii * a.x, ii * b.x); p.x = *(uint*)&h;
    h = __floats2half2_rn(ii * a.y, ii * b.y); p.y = *(uint*)&h;
    h = __floats2half2_rn(ii * a.z, ii * b.z); p.z = *(uint*)&h;
    h = __floats2half2_rn(ii * a.w, ii * b.w); p.w = *(uint*)&h;
    ((uint4*)xout_p)[i] = o;
    ((uint4*)xin_p)[i] = p;
  }
}

// Collapse K=3 weight stacks; pack (wr,wi) as half2: Wh[d*64+o].
__global__ void weights_kernel(const float* __restrict__ Wr, const float* __restrict__ br,
                               const float* __restrict__ Wi, const float* __restrict__ bi,
                               uint* __restrict__ Wh, float* __restrict__ cR,
                               float* __restrict__ cI) {
  int i = blockIdx.x * blockDim.x + threadIdx.x;  // 0..4095 -> (o,d)
  if (i < 4096) {
    int o = i >> 6, d = i & 63;
    float wr = Wr[i] + 0.5f * Wr[4096 + i] + 0.25f * Wr[8192 + i];
    float wi = Wi[i] + 0.5f * Wi[4096 + i] + 0.25f * Wi[8192 + i];
    __half2 h = __floats2half2_rn(wr, wi);
    Wh[d * 64 + o] = *(uint*)&h;
    if (i < 64) {
      float brv = br[i] + 0.5f * br[64 + i] + 0.25f * br[128 + i];
      float biv = bi[i] + 0.5f * bi[64 + i] + 0.25f * bi[128 + i];
      cR[i] = brv - biv;
      cI[i] = brv + biv;
    }
  }
}

// ---------- gather + fused epilogue ----------
// One wave per node. Lane l handles features 4*(l&15)..+3 of edge j+(l>>4):
// one dwordx4 gather covers 4 edges per wave-instruction; unroll 2.
__global__ __launch_bounds__(256) void gather_kernel(
    const uint4* __restrict__ xout4, const uint4* __restrict__ xin4,
    const uint* __restrict__ idx_out, const uint* __restrict__ idx_in,
    const int* __restrict__ ofs_out, const int* __restrict__ ofs_in,
    const float* __restrict__ inv_out, const float* __restrict__ inv_in,
    const uint* __restrict__ Wh, const float* __restrict__ cR, const float* __restrict__ cI,
    float* __restrict__ out_real, float* __restrict__ out_imag, int N) {
  __shared__ uint sW[4096];     // 16 KB half2 weights
  __shared__ float4 sV[4][64];  // 4 KB per-wave staging
  for (int i = threadIdx.x; i < 4096; i += 256) sW[i] = Wh[i];
  __syncthreads();
  int wv = __builtin_amdgcn_readfirstlane(threadIdx.x >> 6);
  int lane = threadIdx.x & 63;
  int sub = lane >> 4;  // edge slot 0..3
  int q = lane & 15;    // uint4 slot -> features 4q..4q+3
  float cRv = cR[lane], cIv = cI[lane];
  float4* mv = &sV[wv][0];
  int wid = blockIdx.x * 4 + wv;
  int nw = gridDim.x * 4;
  for (int n = wid; n < N; n += nw) {
    float4 u1 = {0, 0, 0, 0}, s1 = {0, 0, 0, 0};
    float4 v2 = {0, 0, 0, 0}, s2 = {0, 0, 0, 0};
#define ACC(P, U, S)                                          \
  {                                                           \
    float2 a0 = h2_to_f2((P).x), a1 = h2_to_f2((P).y);        \
    float2 a2 = h2_to_f2((P).z), a3 = h2_to_f2((P).w);        \
    U.x += a0.x; S.x += a0.y; U.y += a1.x; S.y += a1.y;       \
    U.z += a2.x; S.z += a2.y; U.w += a3.x; S.w += a3.y;       \
  }
    {  // out-direction: gathers xin4 (pre-scaled by inv_in of neighbor)
      int lo = ofs_out[n], hi = ofs_out[n + 1];
      int len8 = (hi - lo) & ~7;
      int j = lo;
      for (; j < lo + len8; j += 8) {
        uint4 p0 = xin4[(size_t)idx_out[j + sub] * 16 + q];
        uint4 p1 = xin4[(size_t)idx_out[j + 4 + sub] * 16 + q];
        ACC(p0, u1, s1);
        ACC(p1, u1, s1);
      }
      for (; j < hi; j += 4) {
        if (j + sub < hi) {
          uint4 p0 = xin4[(size_t)idx_out[j + sub] * 16 + q];
          ACC(p0, u1, s1);
        }
      }
    }
    {  // in-direction: gathers xout4 (pre-scaled by inv_out of neighbor)
      int lo = ofs_in[n], hi = ofs_in[n + 1];
      int len8 = (hi - lo) & ~7;
      int j = lo;
      for (; j < lo + len8; j += 8) {
        uint4 p0 = xout4[(size_t)idx_in[j + sub] * 16 + q];
        uint4 p1 = xout4[(size_t)idx_in[j + 4 + sub] * 16 + q];
        ACC(p0, v2, s2);
        ACC(p1, v2, s2);
      }
      for (; j < hi; j += 4) {
        if (j + sub < hi) {
          uint4 p0 = xout4[(size_t)idx_in[j + sub] * 16 + q];
          ACC(p0, v2, s2);
        }
      }
    }
#undef ACC
    // reduce the 4 edge-subgroups (lanes l, l^16, l^32, l^48)
#pragma unroll
    for (int m = 16; m < 64; m <<= 1) {
      u1.x += __shfl_xor(u1.x, m); u1.y += __shfl_xor(u1.y, m);
      u1.z += __shfl_xor(u1.z, m); u1.w += __shfl_xor(u1.w, m);
      s1.x += __shfl_xor(s1.x, m); s1.y += __shfl_xor(s1.y, m);
      s1.z += __shfl_xor(s1.z, m); s1.w += __shfl_xor(s1.w, m);
      v2.x += __shfl_xor(v2.x, m); v2.y += __shfl_xor(v2.y, m);
      v2.z += __shfl_xor(v2.z, m); v2.w += __shfl_xor(v2.w, m);
      s2.x += __shfl_xor(s2.x, m); s2.y += __shfl_xor(s2.y, m);
      s2.z += __shfl_xor(s2.z, m); s2.w += __shfl_xor(s2.w, m);
    }
    float io = inv_out[n], ii = inv_in[n];
    if (sub == 0) {  // stage features 4q..4q+3 -> {p, sh, u}
      float4 uu = {io * u1.x, io * u1.y, io * u1.z, io * u1.w};
      float4 vv = {ii * v2.x, ii * v2.y, ii * v2.z, ii * v2.w};
      float4 ss = {io * s1.x + ii * s2.x, io * s1.y + ii * s2.y,
                   io * s1.z + ii * s2.z, io * s1.w + ii * s2.w};
      mv[4 * q + 0] = make_float4(0.5f * (uu.x + vv.x), 0.5f * ss.x, uu.x, 0.0f);
      mv[4 * q + 1] = make_float4(0.5f * (uu.y + vv.y), 0.5f * ss.y, uu.y, 0.0f);
      mv[4 * q + 2] = make_float4(0.5f * (uu.z + vv.z), 0.5f * ss.z, uu.z, 0.0f);
      mv[4 * q + 3] = make_float4(0.5f * (uu.w + vv.w), 0.5f * ss.w, uu.w, 0.0f);
    }
    // wave-synchronous LDS RAW (same-wave DS ops ordered via lgkmcnt)
    float accR = cRv, accI = cIv;
#pragma unroll 4
    for (int d = 0; d < 64; ++d) {
      float4 pv = mv[d];                        // b128 broadcast
      float2 w2 = h2_to_f2(sW[d * 64 + lane]);  // b32, 2-way alias (free)
      accR += pv.x * w2.x - pv.y * w2.y;
      accI += pv.y * w2.x + pv.z * w2.y;
    }
    out_real[(size_t)n * D + lane] = accR;
    out_imag[(size_t)n * D + lane] = accI;
  }
}

extern "C" void kernel_launch(void* const* d_in, const int* in_sizes, int n_in,
                              void* d_out, int out_size, void* d_ws, size_t ws_size,
                              hipStream_t stream) {
  const float* x_real = (const float*)d_in[0];
  const float* x_imag = (const float*)d_in[1];
  const int* edge = (const int*)d_in[2];
  const float* W_real = (const float*)d_in[3];
  const float* b_real = (const float*)d_in[4];
  const float* W_imag = (const float*)d_in[5];
  const float* b_imag = (const float*)d_in[6];

  const int N = in_sizes[0] / D;  // 100000
  const int E = in_sizes[2] / 2;  // 1600000
  const int* row = edge;
  const int* col = edge + E;

  const int NBUK = (N + 511) >> 9;          // 196 buckets of 512 nodes
  const int CH = (E + G1 - 1) / G1;         // edges per partition block
  const int L = NBUK * G1;                  // flattened histogram length
  const int GB = (L + SB - 1) / SB;         // scan blocks for histograms
  const int NB = (N + SB - 1) / SB;         // scan blocks for degrees

  // workspace layout (16B-aligned packed arrays first)
  uint* xout_p   = (uint*)d_ws;                    // N*64
  uint* xin_p    = xout_p + (size_t)N * D;         // N*64
  uint* pout     = xin_p + (size_t)N * D;          // E (bucketed packs)
  uint* pin      = pout + E;                       // E
  uint* idx_out  = pin + E;                        // E
  uint* idx_in   = idx_out + E;                    // E
  int* hout      = (int*)(idx_in + E);             // L
  int* hin       = hout + L;                       // L
  int* gbs       = hin + L;                        // 2*GB
  int* deg_out   = gbs + 2 * GB;                   // N
  int* deg_in    = deg_out + N;                    // N
  int* ofs_out   = deg_in + N;                     // N+1
  int* ofs_in    = ofs_out + N + 1;                // N+1
  float* inv_out = (float*)(ofs_in + N + 1);       // N
  float* inv_in  = inv_out + N;                    // N
  uint* Wh       = (uint*)(inv_in + N);            // 4096
  float* cR      = (float*)(Wh + 4096);            // 64
  float* cI      = cR + 64;                        // 64
  int* bsum      = (int*)(cI + 64);                // 2*NB

  float* out_real = (float*)d_out;
  float* out_imag = out_real + (size_t)N * D;

  weights_kernel<<<16, 256, 0, stream>>>(W_real, b_real, W_imag, b_imag, Wh, cR, cI);

  // bucket partition of edges (both directions)
  part_count<<<G1, 256, 0, stream>>>(row, col, hout, hin, E, NBUK, CH);
  bsum_kernel<<<dim3(GB, 2), SB, 0, stream>>>(hout, hin, gbs, L, GB);
  bscan_kernel<<<1, 1024, 0, stream>>>(gbs, GB);
  gfin_kernel<<<dim3(GB, 2), SB, 0, stream>>>(hout, hin, gbs, L, GB);
  part_scatter<<<G1, 256, 0, stream>>>(row, col, hout, hin, pout, pin, E, NBUK, CH);

  // per-bucket degrees -> exclusive ofs + inv
  bucket_degree<<<dim3(NBUK, 2), 256, 0, stream>>>(pout, pin, hout, hin,
                                                   deg_out, deg_in, E, NBUK, N);
  bsum_kernel<<<dim3(NB, 2), SB, 0, stream>>>(deg_out, deg_in, bsum, N, NB);
  bscan_kernel<<<1, 1024, 0, stream>>>(bsum, NB);
  sfin_kernel<<<dim3(NB, 2), SB, 0, stream>>>(deg_out, deg_in, bsum, ofs_out, ofs_in,
                                              inv_out, inv_in, N, NB);

  pack_kernel<<<(N * 16 + 255) / 256, 256, 0, stream>>>(x_real, x_imag, inv_out, inv_in,
                                                        xout_p, xin_p, N * 16);
  // per-bucket CSR fill (block-private windows)
  bucket_fill<<<dim3(NBUK, 2), 256, 0, stream>>>(pout, pin, hout, hin, ofs_out, ofs_in,
                                                 idx_out, idx_in, E, NBUK, N);
  gather_kernel<<<4096, 256, 0, stream>>>((const uint4*)xout_p, (const uint4*)xin_p,
                                          idx_out, idx_in, ofs_out, ofs_in,
                                          inv_out, inv_in, Wh, cR, cI,
                                          out_real, out_imag, N);
}